// Round 2
// baseline (570.026 us; speedup 1.0000x reference)
//
#include <hip/hip_runtime.h>
#include <hip/hip_bf16.h>
#include <math.h>

typedef __hip_bfloat16 bf16;
typedef __attribute__((ext_vector_type(8))) short short8;   // 8 bf16 = one MFMA A/B frag
typedef __attribute__((ext_vector_type(4))) float floatx4;  // MFMA C/D frag

constexpr int Bb = 4, Ss = 2048, Dd = 2048, Hh = 16, DKk = 128;
constexpr int KK = 2048, NTt = 32;   // K-dim and #K-tiles (BK=64) for both GEMMs

__device__ __forceinline__ void async_ld16(const bf16* g, bf16* l) {
    __builtin_amdgcn_global_load_lds(
        (__attribute__((address_space(1))) void*)g,
        (__attribute__((address_space(3))) void*)l, 16, 0, 0);
}

__device__ __forceinline__ unsigned int pk2(float a, float b) {
    bf16 ha = __float2bfloat16(a), hb = __float2bfloat16(b);
    unsigned short ua, ub;
    __builtin_memcpy(&ua, &ha, 2);
    __builtin_memcpy(&ub, &hb, 2);
    return (unsigned int)ua | ((unsigned int)ub << 16);
}

// ------- fused prep: fp32->bf16 for x / w_qkv / w_out + RoPE tables -------
__global__ void prep(const float* __restrict__ x, const float* __restrict__ wq,
                     const float* __restrict__ wo,
                     bf16* __restrict__ xb, bf16* __restrict__ wqb,
                     bf16* __restrict__ wob, float2* __restrict__ rt) {
    const int gb = blockIdx.x;
    if (gb < 16384) {
        const float* in; bf16* out; int i;
        if (gb < 8192)       { in = x;  out = xb;  i = gb * 256 + threadIdx.x; }
        else if (gb < 14336) { in = wq; out = wqb; i = (gb - 8192) * 256 + threadIdx.x; }
        else                 { in = wo; out = wob; i = (gb - 14336) * 256 + threadIdx.x; }
        const float4* p = (const float4*)in + 2 * (size_t)i;
        float4 a = p[0], b = p[1];
        float v[8] = {a.x, a.y, a.z, a.w, b.x, b.y, b.z, b.w};
        bf16 h[8];
#pragma unroll
        for (int j = 0; j < 8; j++) h[j] = __float2bfloat16(v[j]);
        __builtin_memcpy(out + 8 * (size_t)i, h, 16);
    } else {
        int i = (gb - 16384) * 256 + threadIdx.x;   // S*64 entries
        int s = i >> 6, f = i & 63;
        float inv_freq = powf(10000.0f, -(float)(2 * f) / 128.0f);
        float ang = (float)s * inv_freq;
        rt[i] = make_float2(cosf(ang), sinf(ang));
    }
}

// stage one 128-row x 64-col (bf16) half-tile of the K-step at src into LDS.
// src must already point at (row0, k0). XOR-8 swizzle applied at the SOURCE so
// the global_load_lds destination stays linear (wave-uniform base + lane*16).
__device__ __forceinline__ void stage_half(const bf16* __restrict__ src,
                                           bf16* __restrict__ dst, int tid) {
#pragma unroll
    for (int c = 0; c < 2; c++) {
        const int idx = c * 512 + tid;          // 1024 16-B chunks total
        const int row = idx >> 3;               // 0..127
        const int sch = (idx & 7) ^ (row & 7);  // swizzled source chunk
        async_ld16(src + (size_t)row * KK + sch * 8, dst + idx * 8);
    }
}

// ---------------- 256x256 8-phase bf16 GEMM: C[M,N] = A[M,K] * B[N,K]^T ----
// 512 threads = 8 waves (2M x 4N); per-wave output 128x64; BK=64.
// LDS 128 KiB: double-buffered A(256x64) + B(256x64).
// Per K-tile: 4 phases x {ds_reads | stage | barrier | 16 MFMA | barrier};
// counted s_waitcnt vmcnt(4) once per tile (never 0 in steady state) keeps
// 2 half-tiles in flight across every tile boundary (T3+T4). T5 setprio
// wraps each MFMA cluster.
template <int EPI>
__global__ __launch_bounds__(512, 2)
void gemm256(const bf16* __restrict__ A, const bf16* __restrict__ Bm, int N,
             float* __restrict__ outF,
             bf16* __restrict__ qb, bf16* __restrict__ kb, bf16* __restrict__ vtb,
             const float2* __restrict__ rope) {
    __shared__ bf16 As[2][256 * 64];   // 64 KB
    __shared__ bf16 Bs[2][256 * 64];   // 64 KB
    const int tid = threadIdx.x;
    const int wave = tid >> 6, lane = tid & 63;
    const int quad = lane >> 4, l16 = lane & 15;
    const int wm = wave >> 2, wn = wave & 3;     // 2 x 4 wave grid
    const int m0 = blockIdx.y * 256;
    const int n0 = blockIdx.x * 256;
    const int swz = l16 & 7;

    const bf16* Arow = A  + (size_t)m0 * KK;
    const bf16* Brow = Bm + (size_t)n0 * KK;

    floatx4 acc[8][4] = {};

    // ---- prologue: stage t0{A0,A1,B0,B1} + t1{A0,A1}; confirm t0 ----
    stage_half(Arow,                         &As[0][0],    tid);
    stage_half(Arow + (size_t)128 * KK,      &As[0][8192], tid);
    stage_half(Brow,                         &Bs[0][0],    tid);
    stage_half(Brow + (size_t)128 * KK,      &Bs[0][8192], tid);
    stage_half(Arow + 64,                    &As[1][0],    tid);
    stage_half(Arow + (size_t)128 * KK + 64, &As[1][8192], tid);
    asm volatile("s_waitcnt vmcnt(4)" ::: "memory");
    __builtin_amdgcn_s_barrier();
    __builtin_amdgcn_sched_barrier(0);

    auto tile = [&](int t, bf16* Ac, bf16* Bc, bf16* An2, bf16* Bn2) {
        short8 aF[4][2], bF[4][2];
        // ---- phase 1: read A[0..3] (kk0,kk1) + B[0..3] kk0 (12 ds_reads);
        //              stage B-half0(t+1) -> next buffer
#pragma unroll
        for (int i = 0; i < 4; i++)
#pragma unroll
            for (int kk = 0; kk < 2; kk++)
                aF[i][kk] = *(const short8*)(Ac + (wm * 128 + i * 16 + l16) * 64 + (((kk * 4 + quad) ^ swz) * 8));
#pragma unroll
        for (int j = 0; j < 4; j++)
            bF[j][0] = *(const short8*)(Bc + (wn * 64 + j * 16 + l16) * 64 + ((quad ^ swz) * 8));
        if (t + 1 < NTt)
            stage_half(Brow + (t + 1) * 64, Bn2, tid);
        __builtin_amdgcn_s_barrier(); __builtin_amdgcn_sched_barrier(0);
        __builtin_amdgcn_s_setprio(1);
#pragma unroll
        for (int i = 0; i < 4; i++)
#pragma unroll
            for (int j = 0; j < 4; j++)
                acc[i][j] = __builtin_amdgcn_mfma_f32_16x16x32_bf16(aF[i][0], bF[j][0], acc[i][j], 0, 0, 0);
        __builtin_amdgcn_s_setprio(0);
        __builtin_amdgcn_s_barrier(); __builtin_amdgcn_sched_barrier(0);

        // ---- phase 2: read B kk1 (4 reads); stage B-half1(t+1)
#pragma unroll
        for (int j = 0; j < 4; j++)
            bF[j][1] = *(const short8*)(Bc + (wn * 64 + j * 16 + l16) * 64 + (((4 + quad) ^ swz) * 8));
        if (t + 1 < NTt)
            stage_half(Brow + (size_t)128 * KK + (t + 1) * 64, Bn2 + 8192, tid);
        __builtin_amdgcn_s_barrier(); __builtin_amdgcn_sched_barrier(0);
        __builtin_amdgcn_s_setprio(1);
#pragma unroll
        for (int i = 0; i < 4; i++)
#pragma unroll
            for (int j = 0; j < 4; j++)
                acc[i][j] = __builtin_amdgcn_mfma_f32_16x16x32_bf16(aF[i][1], bF[j][1], acc[i][j], 0, 0, 0);
        __builtin_amdgcn_s_setprio(0);
        __builtin_amdgcn_s_barrier(); __builtin_amdgcn_sched_barrier(0);

        // ---- phase 3: read A[4..7] (kk0,kk1) (8 reads); no stage
#pragma unroll
        for (int i = 0; i < 4; i++)
#pragma unroll
            for (int kk = 0; kk < 2; kk++)
                aF[i][kk] = *(const short8*)(Ac + (wm * 128 + 64 + i * 16 + l16) * 64 + (((kk * 4 + quad) ^ swz) * 8));
        __builtin_amdgcn_s_barrier(); __builtin_amdgcn_sched_barrier(0);
        __builtin_amdgcn_s_setprio(1);
#pragma unroll
        for (int i = 0; i < 4; i++)
#pragma unroll
            for (int j = 0; j < 4; j++)
                acc[4 + i][j] = __builtin_amdgcn_mfma_f32_16x16x32_bf16(aF[i][0], bF[j][0], acc[4 + i][j], 0, 0, 0);
        __builtin_amdgcn_s_setprio(0);
        __builtin_amdgcn_s_barrier(); __builtin_amdgcn_sched_barrier(0);

        // ---- phase 4: stage A-half0/1(t+2) -> current buffer (all its
        //              ds_reads finished at phase-3's first barrier)
        if (t + 2 < NTt) {
            stage_half(Arow + (t + 2) * 64,                    Ac,        tid);
            stage_half(Arow + (size_t)128 * KK + (t + 2) * 64, Ac + 8192, tid);
        }
        __builtin_amdgcn_s_barrier(); __builtin_amdgcn_sched_barrier(0);
        __builtin_amdgcn_s_setprio(1);
#pragma unroll
        for (int i = 0; i < 4; i++)
#pragma unroll
            for (int j = 0; j < 4; j++)
                acc[4 + i][j] = __builtin_amdgcn_mfma_f32_16x16x32_bf16(aF[i][1], bF[j][1], acc[4 + i][j], 0, 0, 0);
        __builtin_amdgcn_s_setprio(0);
        // tile boundary: confirm everything except phase-4's 4 loads
        if (t + 2 < NTt) { asm volatile("s_waitcnt vmcnt(4)" ::: "memory"); }
        else             { asm volatile("s_waitcnt vmcnt(0)" ::: "memory"); }
        __builtin_amdgcn_s_barrier(); __builtin_amdgcn_sched_barrier(0);
    };

#pragma unroll 1
    for (int t = 0; t < NTt; t += 2) {
        tile(t,     &As[0][0], &Bs[0][0], &As[1][0], &Bs[1][0]);
        tile(t + 1, &As[1][0], &Bs[1][0], &As[0][0], &Bs[0][0]);
    }

    if (EPI == 0) {
#pragma unroll
        for (int i = 0; i < 8; i++) {
            const int gm0 = m0 + wm * 128 + i * 16 + quad * 4;
#pragma unroll
            for (int j = 0; j < 4; j++) {
                const int gn = n0 + wn * 64 + j * 16 + l16;
#pragma unroll
                for (int r = 0; r < 4; r++)
                    outF[(size_t)(gm0 + r) * N + gn] = acc[i][j][r];
            }
        }
    } else {
        const int tq = n0 >> 11;                       // 0=q 1=k 2=v (block-uniform)
        const int h = ((n0 >> 7) + (wn >> 1)) & 15;    // head (thread-uniform)
        const float qscale = 0.08838834764831845f * 1.442695040888963f;
        if (tq < 2) {
#pragma unroll
            for (int j = 0; j < 4; j++) {
                const int d = (wn & 1) * 64 + j * 16 + l16;
#pragma unroll
                for (int i = 0; i < 8; i++) {
#pragma unroll
                    for (int r = 0; r < 4; r++) {
                        const int gm = m0 + wm * 128 + i * 16 + quad * 4 + r;
                        const int b = gm >> 11, s = gm & 2047;
                        const size_t bh = (size_t)(b * Hh + h);
                        float val = acc[i][j][r];
                        float partner = __shfl_xor(val, 1, 64);
                        float2 cs = rope[s * 64 + (d >> 1)];
                        float nv = (d & 1) ? (val * cs.x + partner * cs.y)
                                           : (val * cs.x - partner * cs.y);
                        if (tq == 0) {
                            qb[(bh * Ss + s) * DKk + d] = __float2bfloat16(nv * qscale);
                        } else {
                            kb[(bh * Ss + s) * DKk + d] = __float2bfloat16(nv);
                        }
                    }
                }
            }
        } else {
#pragma unroll
            for (int j = 0; j < 4; j++) {
                const int d = (wn & 1) * 64 + j * 16 + l16;
#pragma unroll
                for (int i = 0; i < 8; i++) {
                    const int gm = m0 + wm * 128 + i * 16 + quad * 4;
                    const int b = gm >> 11, s = gm & 2047;
                    const size_t bh = (size_t)(b * Hh + h);
                    unsigned int w[2];
                    w[0] = pk2(acc[i][j][0], acc[i][j][1]);
                    w[1] = pk2(acc[i][j][2], acc[i][j][3]);
                    __builtin_memcpy(vtb + (bh * DKk + d) * Ss + s, w, 8);
                }
            }
        }
    }
}

// ---------------- flash attention tile body (full vs diagonal) ------------
template <bool DIAG>
__device__ __forceinline__ void attn_tile(
    int c0, int qw0,
    const bf16* __restrict__ kbp, const bf16* __restrict__ vbp,
    bf16* Ks, bf16* Vs,
    const short8 (&qB)[2][4],
    floatx4 (&oacc)[8][2], float (&m_i)[2], float (&l_i)[2],
    int tid, int wave, int quad, int l16, int srow, int chunkg, int swz)
{
    __syncthreads();
#pragma unroll
    for (int r = 0; r < 8; r++) {
        async_ld16(kbp + (size_t)(c0 + r * 16 + srow) * DKk + chunkg * 8,
                   Ks + ((r * 256 + tid) << 3));
        async_ld16(vbp + (size_t)(r * 16 + srow) * Ss + c0 + chunkg * 8,
                   Vs + ((r * 256 + tid) << 3));
    }
    __syncthreads();

    const int lim_n = DIAG ? (wave * 2 + 2) : 8;
    const int lim_k = DIAG ? (wave + 1) : 4;

    // ---- S^T = K Q^T  (q pre-scaled by 1/sqrt(dk)*log2 e) ----
    floatx4 sf[8][2];
#pragma unroll
    for (int n = 0; n < 8; n++) {
        if (n < lim_n) {
            short8 kf[4];
#pragma unroll
            for (int kk = 0; kk < 4; kk++)
                kf[kk] = *(const short8*)(Ks + (n * 16 + l16) * 128 + (((kk * 4 + quad) ^ swz) * 8));
            sf[n][0] = (floatx4){0.f, 0.f, 0.f, 0.f};
            sf[n][1] = (floatx4){0.f, 0.f, 0.f, 0.f};
#pragma unroll
            for (int kk = 0; kk < 4; kk++) {
                sf[n][0] = __builtin_amdgcn_mfma_f32_16x16x32_bf16(kf[kk], qB[0][kk], sf[n][0], 0, 0, 0);
                sf[n][1] = __builtin_amdgcn_mfma_f32_16x16x32_bf16(kf[kk], qB[1][kk], sf[n][1], 0, 0, 0);
            }
        }
    }

    // ---- online softmax (base-2; state per l16 lane, replicated in quads) ----
    unsigned int pp01[8][2], pp23[8][2];
#pragma unroll
    for (int qf = 0; qf < 2; qf++) {
        float mx = -__builtin_inff();
        if (DIAG) {
            const int qrow = qw0 + qf * 16 + l16;
#pragma unroll
            for (int n = 0; n < 8; n++) {
                if (n < lim_n) {
                    const int kvb = c0 + n * 16 + quad * 4;
#pragma unroll
                    for (int r = 0; r < 4; r++) {
                        float v = sf[n][qf][r];
                        v = (kvb + r > qrow) ? -__builtin_inff() : v;
                        sf[n][qf][r] = v;
                        mx = fmaxf(mx, v);
                    }
                }
            }
        } else {
#pragma unroll
            for (int n = 0; n < 8; n++)
#pragma unroll
                for (int r = 0; r < 4; r++) mx = fmaxf(mx, sf[n][qf][r]);
        }
        mx = fmaxf(mx, __shfl_xor(mx, 16, 64));
        mx = fmaxf(mx, __shfl_xor(mx, 32, 64));
        const float mnew = fmaxf(m_i[qf], mx);
        const float alpha = __builtin_amdgcn_exp2f(m_i[qf] - mnew);
        m_i[qf] = mnew;
        float rs = 0.f;
#pragma unroll
        for (int n = 0; n < 8; n++) {
            if (n < lim_n) {
                float p0 = __builtin_amdgcn_exp2f(sf[n][qf][0] - mnew);
                float p1 = __builtin_amdgcn_exp2f(sf[n][qf][1] - mnew);
                float p2 = __builtin_amdgcn_exp2f(sf[n][qf][2] - mnew);
                float p3 = __builtin_amdgcn_exp2f(sf[n][qf][3] - mnew);
                rs += (p0 + p1) + (p2 + p3);
                pp01[n][qf] = pk2(p0, p1);
                pp23[n][qf] = pk2(p2, p3);
            }
        }
        rs += __shfl_xor(rs, 16, 64);
        rs += __shfl_xor(rs, 32, 64);
        l_i[qf] = l_i[qf] * alpha + rs;
#pragma unroll
        for (int md = 0; md < 8; md++)
#pragma unroll
            for (int r = 0; r < 4; r++) oacc[md][qf][r] *= alpha;
    }

    // ---- O^T += V^T P^T  (P^T B-frags built in-register via shuffles) ----
    const int srcA = ((quad & 1) * 2) * 16 + l16;
    const int srcB = srcA + 16;
#pragma unroll
    for (int kv = 0; kv < 4; kv++) {
        if (kv < lim_k) {
            short8 pB[2];
#pragma unroll
            for (int qf = 0; qf < 2; qf++) {
                unsigned int a01 = (unsigned int)__shfl((int)pp01[2 * kv][qf], srcA, 64);
                unsigned int a23 = (unsigned int)__shfl((int)pp23[2 * kv][qf], srcA, 64);
                unsigned int a45 = (unsigned int)__shfl((int)pp01[2 * kv][qf], srcB, 64);
                unsigned int a67 = (unsigned int)__shfl((int)pp23[2 * kv][qf], srcB, 64);
                unsigned int b01 = (unsigned int)__shfl((int)pp01[2 * kv + 1][qf], srcA, 64);
                unsigned int b23 = (unsigned int)__shfl((int)pp23[2 * kv + 1][qf], srcA, 64);
                unsigned int b45 = (unsigned int)__shfl((int)pp01[2 * kv + 1][qf], srcB, 64);
                unsigned int b67 = (unsigned int)__shfl((int)pp23[2 * kv + 1][qf], srcB, 64);
                const bool hi = quad >= 2;
                unsigned int e[4];
                e[0] = hi ? b01 : a01;
                e[1] = hi ? b23 : a23;
                e[2] = hi ? b45 : a45;
                e[3] = hi ? b67 : a67;
                __builtin_memcpy(&pB[qf], e, 16);
            }
#pragma unroll
            for (int md = 0; md < 8; md++) {
                short8 vf = *(const short8*)(Vs + (md * 16 + l16) * 128 + (((kv * 4 + quad) ^ swz) * 8));
                oacc[md][0] = __builtin_amdgcn_mfma_f32_16x16x32_bf16(vf, pB[0], oacc[md][0], 0, 0, 0);
                oacc[md][1] = __builtin_amdgcn_mfma_f32_16x16x32_bf16(vf, pB[1], oacc[md][1], 0, 0, 0);
            }
        }
    }
}

// ---------------- flash attention (balanced q-tile pairing) ----------------
// grid (8, B*H): block xp processes q-tiles {15-xp, xp} sequentially ->
// every block does exactly 17 tile-units; 512 blocks = exactly 2/CU, no tail.
__global__ __launch_bounds__(256, 2)
void flash_attn(const bf16* __restrict__ q, const bf16* __restrict__ k,
                const bf16* __restrict__ vt, bf16* __restrict__ o) {
    __shared__ bf16 Ks[128 * 128];   // 32 KB  rows=kv, cols=d
    __shared__ bf16 Vs[128 * 128];   // 32 KB  rows=d,  cols=kv
    const int tid = threadIdx.x, wave = tid >> 6, lane = tid & 63;
    const int quad = lane >> 4, l16 = lane & 15;
    const int bh = blockIdx.y;
    const int xp = blockIdx.x;       // 0..7
    const bf16* qbp = q  + (size_t)bh * Ss * DKk;
    const bf16* kbp = k  + (size_t)bh * Ss * DKk;
    const bf16* vbp = vt + (size_t)bh * DKk * Ss;
    const int b = bh >> 4, h = bh & 15;

    const int srow = tid >> 4;
    const int chunkg = (tid & 15) ^ (srow & 7);
    const int swz = (l16 & 7);

    for (int pass = 0; pass < 2; ++pass) {
        const int xq = pass ? xp : 15 - xp;
        const int qw0 = xq * 128 + wave * 32;

        short8 qB[2][4];
#pragma unroll
        for (int qf = 0; qf < 2; qf++)
#pragma unroll
            for (int kk = 0; kk < 4; kk++)
                qB[qf][kk] = *(const short8*)(qbp + (size_t)(qw0 + qf * 16 + l16) * DKk + kk * 32 + quad * 8);

        floatx4 oacc[8][2] = {};
        float m_i[2] = {-__builtin_inff(), -__builtin_inff()};
        float l_i[2] = {0.f, 0.f};

        for (int it = 0; it < xq; ++it)
            attn_tile<false>(it * 128, qw0, kbp, vbp, Ks, Vs, qB, oacc, m_i, l_i,
                             tid, wave, quad, l16, srow, chunkg, swz);
        attn_tile<true>(xq * 128, qw0, kbp, vbp, Ks, Vs, qB, oacc, m_i, l_i,
                        tid, wave, quad, l16, srow, chunkg, swz);

#pragma unroll
        for (int qf = 0; qf < 2; qf++) {
            const float inv = 1.0f / l_i[qf];
            const int s = qw0 + qf * 16 + l16;
            bf16* orow = o + (size_t)(b * Ss + s) * Dd + h * 128;
#pragma unroll
            for (int md = 0; md < 8; md++) {
                unsigned int w[2];
                w[0] = pk2(oacc[md][qf][0] * inv, oacc[md][qf][1] * inv);
                w[1] = pk2(oacc[md][qf][2] * inv, oacc[md][qf][3] * inv);
                __builtin_memcpy(orow + md * 16 + quad * 4, w, 8);
            }
        }
    }
}

extern "C" void kernel_launch(void* const* d_in, const int* in_sizes, int n_in,
                              void* d_out, int out_size, void* d_ws, size_t ws_size,
                              hipStream_t stream) {
    const float* x     = (const float*)d_in[0];
    const float* w_qkv = (const float*)d_in[1];
    const float* w_out = (const float*)d_in[2];
    float* out = (float*)d_out;
    char* ws = (char*)d_ws;

    bf16*   xb  = (bf16*)(ws);                 // 32 MiB  x bf16; reused as attn output
    bf16*   wqb = (bf16*)(ws + 33554432);      // 24 MiB  w_qkv bf16
    bf16*   wob = (bf16*)(ws + 58720256);      //  8 MiB  w_out bf16
    bf16*   qb  = (bf16*)(ws + 67108864);      // 32 MiB  q   [B,H,S,dk] (pre-scaled)
    bf16*   kb  = (bf16*)(ws + 100663296);     // 32 MiB  k   [B,H,S,dk]
    bf16*   vtb = (bf16*)(ws + 134217728);     // 32 MiB  v^T [B,H,dk,S]
    float2* rt  = (float2*)(ws + 167772160);   //  1 MiB  rope tables

    prep<<<16896, 256, 0, stream>>>(x, w_qkv, w_out, xb, wqb, wob, rt);

    gemm256<1><<<dim3(24, 32), 512, 0, stream>>>(xb, wqb, 6144,
                                                 nullptr, qb, kb, vtb, rt);
    flash_attn<<<dim3(8, 64), 256, 0, stream>>>(qb, kb, vtb, xb);
    gemm256<0><<<dim3(8, 32), 512, 0, stream>>>(xb, wob, 2048,
                                                out, nullptr, nullptr, nullptr, rt);
}

// Round 3
// 567.353 us; speedup vs baseline: 1.0047x; 1.0047x over previous
//
#include <hip/hip_runtime.h>
#include <hip/hip_bf16.h>
#include <math.h>

typedef __hip_bfloat16 bf16;
typedef __attribute__((ext_vector_type(8))) short short8;   // 8 bf16 = one MFMA A/B frag
typedef __attribute__((ext_vector_type(4))) float floatx4;  // MFMA C/D frag

constexpr int Bb = 4, Ss = 2048, Dd = 2048, Hh = 16, DKk = 128;
constexpr int KK = 2048, NTt = 32;   // K-dim and #K-tiles (BK=64) for both GEMMs

__device__ __forceinline__ void async_ld16(const bf16* g, bf16* l) {
    __builtin_amdgcn_global_load_lds(
        (__attribute__((address_space(1))) void*)g,
        (__attribute__((address_space(3))) void*)l, 16, 0, 0);
}

__device__ __forceinline__ unsigned int pk2(float a, float b) {
    bf16 ha = __float2bfloat16(a), hb = __float2bfloat16(b);
    unsigned short ua, ub;
    __builtin_memcpy(&ua, &ha, 2);
    __builtin_memcpy(&ub, &hb, 2);
    return (unsigned int)ua | ((unsigned int)ub << 16);
}

// ------- fused prep: fp32->bf16 for x / w_qkv / w_out + RoPE tables -------
__global__ void prep(const float* __restrict__ x, const float* __restrict__ wq,
                     const float* __restrict__ wo,
                     bf16* __restrict__ xb, bf16* __restrict__ wqb,
                     bf16* __restrict__ wob, float2* __restrict__ rt) {
    const int gb = blockIdx.x;
    if (gb < 16384) {
        const float* in; bf16* out; int i;
        if (gb < 8192)       { in = x;  out = xb;  i = gb * 256 + threadIdx.x; }
        else if (gb < 14336) { in = wq; out = wqb; i = (gb - 8192) * 256 + threadIdx.x; }
        else                 { in = wo; out = wob; i = (gb - 14336) * 256 + threadIdx.x; }
        const float4* p = (const float4*)in + 2 * (size_t)i;
        float4 a = p[0], b = p[1];
        float v[8] = {a.x, a.y, a.z, a.w, b.x, b.y, b.z, b.w};
        bf16 h[8];
#pragma unroll
        for (int j = 0; j < 8; j++) h[j] = __float2bfloat16(v[j]);
        __builtin_memcpy(out + 8 * (size_t)i, h, 16);
    } else {
        int i = (gb - 16384) * 256 + threadIdx.x;   // S*64 entries
        int s = i >> 6, f = i & 63;
        float inv_freq = powf(10000.0f, -(float)(2 * f) / 128.0f);
        float ang = (float)s * inv_freq;
        rt[i] = make_float2(cosf(ang), sinf(ang));
    }
}

// stage one 128-row x 64-col (bf16) half-tile of the K-step at src into LDS.
// src must already point at (row0, k0). XOR-8 swizzle applied at the SOURCE so
// the global_load_lds destination stays linear (wave-uniform base + lane*16).
__device__ __forceinline__ void stage_half(const bf16* __restrict__ src,
                                           bf16* __restrict__ dst, int tid) {
#pragma unroll
    for (int c = 0; c < 2; c++) {
        const int idx = c * 512 + tid;          // 1024 16-B chunks total
        const int row = idx >> 3;               // 0..127
        const int sch = (idx & 7) ^ (row & 7);  // swizzled source chunk
        async_ld16(src + (size_t)row * KK + sch * 8, dst + idx * 8);
    }
}

// ---------------- 256x256 8-phase bf16 GEMM: C[M,N] = A[M,K] * B[N,K]^T ----
// 512 threads = 8 waves (2M x 4N); per-wave output 128x64; BK=64.
// LDS 128 KiB: double-buffered A(256x64) + B(256x64).
// Per K-tile: 4 phases x {ds_reads | stage | barrier | 16 MFMA | barrier}.
// Staging: B(t+1) phases 1-2 (cross-buffer), A(t+2) phase 4 (current buffer,
// after all its ds_reads were consumed -> race-free). Counted vmcnt(4) once
// per tile boundary keeps A(t+2)'s 2 half-tiles in flight (T3+T4); never 0
// in steady state. T5 setprio wraps each MFMA cluster. NO sched_barriers
// (m141: order-pinning costs ~40%).
template <int EPI>
__global__ __launch_bounds__(512, 2)
void gemm256(const bf16* __restrict__ A, const bf16* __restrict__ Bm, int N,
             float* __restrict__ outF,
             bf16* __restrict__ qb, bf16* __restrict__ kb, bf16* __restrict__ vtb,
             const float2* __restrict__ rope) {
    __shared__ bf16 As[2][256 * 64];   // 64 KB
    __shared__ bf16 Bs[2][256 * 64];   // 64 KB
    const int tid = threadIdx.x;
    const int wave = tid >> 6, lane = tid & 63;
    const int quad = lane >> 4, l16 = lane & 15;
    const int wm = wave >> 2, wn = wave & 3;     // 2 x 4 wave grid
    const int m0 = blockIdx.y * 256;
    const int n0 = blockIdx.x * 256;
    const int swz = l16 & 7;

    const bf16* Arow = A  + (size_t)m0 * KK;
    const bf16* Brow = Bm + (size_t)n0 * KK;

    floatx4 acc[8][4] = {};

    // ---- prologue: stage t0{A0,A1,B0,B1} + t1{A0,A1}; confirm t0 ----
    stage_half(Arow,                         &As[0][0],    tid);
    stage_half(Arow + (size_t)128 * KK,      &As[0][8192], tid);
    stage_half(Brow,                         &Bs[0][0],    tid);
    stage_half(Brow + (size_t)128 * KK,      &Bs[0][8192], tid);
    stage_half(Arow + 64,                    &As[1][0],    tid);
    stage_half(Arow + (size_t)128 * KK + 64, &As[1][8192], tid);
    asm volatile("s_waitcnt vmcnt(4)" ::: "memory");
    __builtin_amdgcn_s_barrier();

    auto tile = [&](int t, bf16* Ac, bf16* Bc, bf16* Bn) {
        short8 a03[4][2], a47[4][2], bF[4][2];
        // ---- phase 1: reads A03kk0 -> Bkk0 -> A03kk1 (needed-first order);
        //              stage B-half0(t+1) -> next buffer (cross-buffer safe)
#pragma unroll
        for (int i = 0; i < 4; i++)
            a03[i][0] = *(const short8*)(Ac + (wm * 128 + i * 16 + l16) * 64 + ((quad ^ swz) * 8));
#pragma unroll
        for (int j = 0; j < 4; j++)
            bF[j][0] = *(const short8*)(Bc + (wn * 64 + j * 16 + l16) * 64 + ((quad ^ swz) * 8));
#pragma unroll
        for (int i = 0; i < 4; i++)
            a03[i][1] = *(const short8*)(Ac + (wm * 128 + i * 16 + l16) * 64 + (((4 + quad) ^ swz) * 8));
        if (t + 1 < NTt)
            stage_half(Brow + (t + 1) * 64, Bn, tid);
        __builtin_amdgcn_s_barrier();
        __builtin_amdgcn_s_setprio(1);
#pragma unroll
        for (int i = 0; i < 4; i++)
#pragma unroll
            for (int j = 0; j < 4; j++)
                acc[i][j] = __builtin_amdgcn_mfma_f32_16x16x32_bf16(a03[i][0], bF[j][0], acc[i][j], 0, 0, 0);
        __builtin_amdgcn_s_setprio(0);
        __builtin_amdgcn_s_barrier();

        // ---- phase 2: reads Bkk1 -> A47kk0; stage B-half1(t+1)
#pragma unroll
        for (int j = 0; j < 4; j++)
            bF[j][1] = *(const short8*)(Bc + (wn * 64 + j * 16 + l16) * 64 + (((4 + quad) ^ swz) * 8));
#pragma unroll
        for (int i = 0; i < 4; i++)
            a47[i][0] = *(const short8*)(Ac + (wm * 128 + 64 + i * 16 + l16) * 64 + ((quad ^ swz) * 8));
        if (t + 1 < NTt)
            stage_half(Brow + (size_t)128 * KK + (t + 1) * 64, Bn + 8192, tid);
        __builtin_amdgcn_s_barrier();
        __builtin_amdgcn_s_setprio(1);
#pragma unroll
        for (int i = 0; i < 4; i++)
#pragma unroll
            for (int j = 0; j < 4; j++)
                acc[i][j] = __builtin_amdgcn_mfma_f32_16x16x32_bf16(a03[i][1], bF[j][1], acc[i][j], 0, 0, 0);
        __builtin_amdgcn_s_setprio(0);
        __builtin_amdgcn_s_barrier();

        // ---- phase 3: reads A47kk1; no stage
#pragma unroll
        for (int i = 0; i < 4; i++)
            a47[i][1] = *(const short8*)(Ac + (wm * 128 + 64 + i * 16 + l16) * 64 + (((4 + quad) ^ swz) * 8));
        __builtin_amdgcn_s_barrier();
        __builtin_amdgcn_s_setprio(1);
#pragma unroll
        for (int i = 0; i < 4; i++)
#pragma unroll
            for (int j = 0; j < 4; j++)
                acc[4 + i][j] = __builtin_amdgcn_mfma_f32_16x16x32_bf16(a47[i][0], bF[j][0], acc[4 + i][j], 0, 0, 0);
        __builtin_amdgcn_s_setprio(0);
        __builtin_amdgcn_s_barrier();

        // ---- phase 4: stage A-half0/1(t+2) -> current buffer (all its
        //              ds_reads were consumed before phase-3's end barrier)
        if (t + 2 < NTt) {
            stage_half(Arow + (t + 2) * 64,                    Ac,        tid);
            stage_half(Arow + (size_t)128 * KK + (t + 2) * 64, Ac + 8192, tid);
        }
        __builtin_amdgcn_s_barrier();
        __builtin_amdgcn_s_setprio(1);
#pragma unroll
        for (int i = 0; i < 4; i++)
#pragma unroll
            for (int j = 0; j < 4; j++)
                acc[4 + i][j] = __builtin_amdgcn_mfma_f32_16x16x32_bf16(a47[i][1], bF[j][1], acc[4 + i][j], 0, 0, 0);
        __builtin_amdgcn_s_setprio(0);
        // tile boundary: confirm tile t+1; keep A(t+2)'s 4 loads in flight
        if (t + 2 < NTt) { asm volatile("s_waitcnt vmcnt(4)" ::: "memory"); }
        else             { asm volatile("s_waitcnt vmcnt(0)" ::: "memory"); }
        __builtin_amdgcn_s_barrier();
    };

#pragma unroll 1
    for (int t = 0; t < NTt; t += 2) {
        tile(t,     &As[0][0], &Bs[0][0], &Bs[1][0]);
        tile(t + 1, &As[1][0], &Bs[1][0], &Bs[0][0]);
    }

    if (EPI == 0) {
#pragma unroll
        for (int i = 0; i < 8; i++) {
            const int gm0 = m0 + wm * 128 + i * 16 + quad * 4;
#pragma unroll
            for (int j = 0; j < 4; j++) {
                const int gn = n0 + wn * 64 + j * 16 + l16;
#pragma unroll
                for (int r = 0; r < 4; r++)
                    outF[(size_t)(gm0 + r) * N + gn] = acc[i][j][r];
            }
        }
    } else {
        const int tq = n0 >> 11;                       // 0=q 1=k 2=v (block-uniform)
        const int h = ((n0 >> 7) + (wn >> 1)) & 15;    // head (thread-uniform)
        const float qscale = 0.08838834764831845f * 1.442695040888963f;
        if (tq < 2) {
#pragma unroll
            for (int j = 0; j < 4; j++) {
                const int d = (wn & 1) * 64 + j * 16 + l16;
#pragma unroll
                for (int i = 0; i < 8; i++) {
#pragma unroll
                    for (int r = 0; r < 4; r++) {
                        const int gm = m0 + wm * 128 + i * 16 + quad * 4 + r;
                        const int b = gm >> 11, s = gm & 2047;
                        const size_t bh = (size_t)(b * Hh + h);
                        float val = acc[i][j][r];
                        float partner = __shfl_xor(val, 1, 64);
                        float2 cs = rope[s * 64 + (d >> 1)];
                        float nv = (d & 1) ? (val * cs.x + partner * cs.y)
                                           : (val * cs.x - partner * cs.y);
                        if (tq == 0) {
                            qb[(bh * Ss + s) * DKk + d] = __float2bfloat16(nv * qscale);
                        } else {
                            kb[(bh * Ss + s) * DKk + d] = __float2bfloat16(nv);
                        }
                    }
                }
            }
        } else {
#pragma unroll
            for (int j = 0; j < 4; j++) {
                const int d = (wn & 1) * 64 + j * 16 + l16;
#pragma unroll
                for (int i = 0; i < 8; i++) {
                    const int gm = m0 + wm * 128 + i * 16 + quad * 4;
                    const int b = gm >> 11, s = gm & 2047;
                    const size_t bh = (size_t)(b * Hh + h);
                    unsigned int w[2];
                    w[0] = pk2(acc[i][j][0], acc[i][j][1]);
                    w[1] = pk2(acc[i][j][2], acc[i][j][3]);
                    __builtin_memcpy(vtb + (bh * DKk + d) * Ss + s, w, 8);
                }
            }
        }
    }
}

// ---------------- flash attention tile body (full vs diagonal) ------------
template <bool DIAG>
__device__ __forceinline__ void attn_tile(
    int c0, int qw0,
    const bf16* __restrict__ kbp, const bf16* __restrict__ vbp,
    bf16* Ks, bf16* Vs,
    const short8 (&qB)[2][4],
    floatx4 (&oacc)[8][2], float (&m_i)[2], float (&l_i)[2],
    int tid, int wave, int quad, int l16, int srow, int chunkg, int swz)
{
    __syncthreads();
#pragma unroll
    for (int r = 0; r < 8; r++) {
        async_ld16(kbp + (size_t)(c0 + r * 16 + srow) * DKk + chunkg * 8,
                   Ks + ((r * 256 + tid) << 3));
        async_ld16(vbp + (size_t)(r * 16 + srow) * Ss + c0 + chunkg * 8,
                   Vs + ((r * 256 + tid) << 3));
    }
    __syncthreads();

    const int lim_n = DIAG ? (wave * 2 + 2) : 8;
    const int lim_k = DIAG ? (wave + 1) : 4;

    // ---- S^T = K Q^T  (q pre-scaled by 1/sqrt(dk)*log2 e) ----
    floatx4 sf[8][2];
#pragma unroll
    for (int n = 0; n < 8; n++) {
        if (n < lim_n) {
            short8 kf[4];
#pragma unroll
            for (int kk = 0; kk < 4; kk++)
                kf[kk] = *(const short8*)(Ks + (n * 16 + l16) * 128 + (((kk * 4 + quad) ^ swz) * 8));
            sf[n][0] = (floatx4){0.f, 0.f, 0.f, 0.f};
            sf[n][1] = (floatx4){0.f, 0.f, 0.f, 0.f};
#pragma unroll
            for (int kk = 0; kk < 4; kk++) {
                sf[n][0] = __builtin_amdgcn_mfma_f32_16x16x32_bf16(kf[kk], qB[0][kk], sf[n][0], 0, 0, 0);
                sf[n][1] = __builtin_amdgcn_mfma_f32_16x16x32_bf16(kf[kk], qB[1][kk], sf[n][1], 0, 0, 0);
            }
        }
    }

    // ---- online softmax (base-2; state per l16 lane, replicated in quads) ----
    unsigned int pp01[8][2], pp23[8][2];
#pragma unroll
    for (int qf = 0; qf < 2; qf++) {
        float mx = -__builtin_inff();
        if (DIAG) {
            const int qrow = qw0 + qf * 16 + l16;
#pragma unroll
            for (int n = 0; n < 8; n++) {
                if (n < lim_n) {
                    const int kvb = c0 + n * 16 + quad * 4;
#pragma unroll
                    for (int r = 0; r < 4; r++) {
                        float v = sf[n][qf][r];
                        v = (kvb + r > qrow) ? -__builtin_inff() : v;
                        sf[n][qf][r] = v;
                        mx = fmaxf(mx, v);
                    }
                }
            }
        } else {
#pragma unroll
            for (int n = 0; n < 8; n++)
#pragma unroll
                for (int r = 0; r < 4; r++) mx = fmaxf(mx, sf[n][qf][r]);
        }
        mx = fmaxf(mx, __shfl_xor(mx, 16, 64));
        mx = fmaxf(mx, __shfl_xor(mx, 32, 64));
        const float mnew = fmaxf(m_i[qf], mx);
        const float alpha = __builtin_amdgcn_exp2f(m_i[qf] - mnew);
        m_i[qf] = mnew;
        float rs = 0.f;
#pragma unroll
        for (int n = 0; n < 8; n++) {
            if (n < lim_n) {
                float p0 = __builtin_amdgcn_exp2f(sf[n][qf][0] - mnew);
                float p1 = __builtin_amdgcn_exp2f(sf[n][qf][1] - mnew);
                float p2 = __builtin_amdgcn_exp2f(sf[n][qf][2] - mnew);
                float p3 = __builtin_amdgcn_exp2f(sf[n][qf][3] - mnew);
                rs += (p0 + p1) + (p2 + p3);
                pp01[n][qf] = pk2(p0, p1);
                pp23[n][qf] = pk2(p2, p3);
            }
        }
        rs += __shfl_xor(rs, 16, 64);
        rs += __shfl_xor(rs, 32, 64);
        l_i[qf] = l_i[qf] * alpha + rs;
#pragma unroll
        for (int md = 0; md < 8; md++)
#pragma unroll
            for (int r = 0; r < 4; r++) oacc[md][qf][r] *= alpha;
    }

    // ---- O^T += V^T P^T  (P^T B-frags built in-register via shuffles) ----
    const int srcA = ((quad & 1) * 2) * 16 + l16;
    const int srcB = srcA + 16;
#pragma unroll
    for (int kv = 0; kv < 4; kv++) {
        if (kv < lim_k) {
            short8 pB[2];
#pragma unroll
            for (int qf = 0; qf < 2; qf++) {
                unsigned int a01 = (unsigned int)__shfl((int)pp01[2 * kv][qf], srcA, 64);
                unsigned int a23 = (unsigned int)__shfl((int)pp23[2 * kv][qf], srcA, 64);
                unsigned int a45 = (unsigned int)__shfl((int)pp01[2 * kv][qf], srcB, 64);
                unsigned int a67 = (unsigned int)__shfl((int)pp23[2 * kv][qf], srcB, 64);
                unsigned int b01 = (unsigned int)__shfl((int)pp01[2 * kv + 1][qf], srcA, 64);
                unsigned int b23 = (unsigned int)__shfl((int)pp23[2 * kv + 1][qf], srcA, 64);
                unsigned int b45 = (unsigned int)__shfl((int)pp01[2 * kv + 1][qf], srcB, 64);
                unsigned int b67 = (unsigned int)__shfl((int)pp23[2 * kv + 1][qf], srcB, 64);
                const bool hi = quad >= 2;
                unsigned int e[4];
                e[0] = hi ? b01 : a01;
                e[1] = hi ? b23 : a23;
                e[2] = hi ? b45 : a45;
                e[3] = hi ? b67 : a67;
                __builtin_memcpy(&pB[qf], e, 16);
            }
#pragma unroll
            for (int md = 0; md < 8; md++) {
                short8 vf = *(const short8*)(Vs + (md * 16 + l16) * 128 + (((kv * 4 + quad) ^ swz) * 8));
                oacc[md][0] = __builtin_amdgcn_mfma_f32_16x16x32_bf16(vf, pB[0], oacc[md][0], 0, 0, 0);
                oacc[md][1] = __builtin_amdgcn_mfma_f32_16x16x32_bf16(vf, pB[1], oacc[md][1], 0, 0, 0);
            }
        }
    }
}

// ---------------- flash attention (balanced q-tile pairing) ----------------
// grid (8, B*H): block xp processes q-tiles {15-xp, xp} sequentially ->
// every block does exactly 17 tile-units; 512 blocks = exactly 2/CU, no tail.
__global__ __launch_bounds__(256, 2)
void flash_attn(const bf16* __restrict__ q, const bf16* __restrict__ k,
                const bf16* __restrict__ vt, bf16* __restrict__ o) {
    __shared__ bf16 Ks[128 * 128];   // 32 KB  rows=kv, cols=d
    __shared__ bf16 Vs[128 * 128];   // 32 KB  rows=d,  cols=kv
    const int tid = threadIdx.x, wave = tid >> 6, lane = tid & 63;
    const int quad = lane >> 4, l16 = lane & 15;
    const int bh = blockIdx.y;
    const int xp = blockIdx.x;       // 0..7
    const bf16* qbp = q  + (size_t)bh * Ss * DKk;
    const bf16* kbp = k  + (size_t)bh * Ss * DKk;
    const bf16* vbp = vt + (size_t)bh * DKk * Ss;
    const int b = bh >> 4, h = bh & 15;

    const int srow = tid >> 4;
    const int chunkg = (tid & 15) ^ (srow & 7);
    const int swz = (l16 & 7);

    for (int pass = 0; pass < 2; ++pass) {
        const int xq = pass ? xp : 15 - xp;
        const int qw0 = xq * 128 + wave * 32;

        short8 qB[2][4];
#pragma unroll
        for (int qf = 0; qf < 2; qf++)
#pragma unroll
            for (int kk = 0; kk < 4; kk++)
                qB[qf][kk] = *(const short8*)(qbp + (size_t)(qw0 + qf * 16 + l16) * DKk + kk * 32 + quad * 8);

        floatx4 oacc[8][2] = {};
        float m_i[2] = {-__builtin_inff(), -__builtin_inff()};
        float l_i[2] = {0.f, 0.f};

        for (int it = 0; it < xq; ++it)
            attn_tile<false>(it * 128, qw0, kbp, vbp, Ks, Vs, qB, oacc, m_i, l_i,
                             tid, wave, quad, l16, srow, chunkg, swz);
        attn_tile<true>(xq * 128, qw0, kbp, vbp, Ks, Vs, qB, oacc, m_i, l_i,
                        tid, wave, quad, l16, srow, chunkg, swz);

#pragma unroll
        for (int qf = 0; qf < 2; qf++) {
            const float inv = 1.0f / l_i[qf];
            const int s = qw0 + qf * 16 + l16;
            bf16* orow = o + (size_t)(b * Ss + s) * Dd + h * 128;
#pragma unroll
            for (int md = 0; md < 8; md++) {
                unsigned int w[2];
                w[0] = pk2(oacc[md][qf][0] * inv, oacc[md][qf][1] * inv);
                w[1] = pk2(oacc[md][qf][2] * inv, oacc[md][qf][3] * inv);
                __builtin_memcpy(orow + md * 16 + quad * 4, w, 8);
            }
        }
    }
}

extern "C" void kernel_launch(void* const* d_in, const int* in_sizes, int n_in,
                              void* d_out, int out_size, void* d_ws, size_t ws_size,
                              hipStream_t stream) {
    const float* x     = (const float*)d_in[0];
    const float* w_qkv = (const float*)d_in[1];
    const float* w_out = (const float*)d_in[2];
    float* out = (float*)d_out;
    char* ws = (char*)d_ws;

    bf16*   xb  = (bf16*)(ws);                 // 32 MiB  x bf16; reused as attn output
    bf16*   wqb = (bf16*)(ws + 33554432);      // 24 MiB  w_qkv bf16
    bf16*   wob = (bf16*)(ws + 58720256);      //  8 MiB  w_out bf16
    bf16*   qb  = (bf16*)(ws + 67108864);      // 32 MiB  q   [B,H,S,dk] (pre-scaled)
    bf16*   kb  = (bf16*)(ws + 100663296);     // 32 MiB  k   [B,H,S,dk]
    bf16*   vtb = (bf16*)(ws + 134217728);     // 32 MiB  v^T [B,H,dk,S]
    float2* rt  = (float2*)(ws + 167772160);   //  1 MiB  rope tables

    prep<<<16896, 256, 0, stream>>>(x, w_qkv, w_out, xb, wqb, wob, rt);

    gemm256<1><<<dim3(24, 32), 512, 0, stream>>>(xb, wqb, 6144,
                                                 nullptr, qb, kb, vtb, rt);
    flash_attn<<<dim3(8, 64), 256, 0, stream>>>(qb, kb, vtb, xb);
    gemm256<0><<<dim3(8, 32), 512, 0, stream>>>(xb, wob, 2048,
                                                out, nullptr, nullptr, nullptr, rt);
}

// Round 4
// 535.577 us; speedup vs baseline: 1.0643x; 1.0593x over previous
//
#include <hip/hip_runtime.h>
#include <hip/hip_bf16.h>
#include <math.h>

typedef __hip_bfloat16 bf16;
typedef __attribute__((ext_vector_type(8))) short short8;   // 8 bf16 = one MFMA A/B frag
typedef __attribute__((ext_vector_type(4))) float floatx4;  // MFMA C/D frag

constexpr int Bb = 4, Ss = 2048, Dd = 2048, Hh = 16, DKk = 128;

__device__ __forceinline__ void async_ld16(const bf16* g, bf16* l) {
    __builtin_amdgcn_global_load_lds(
        (__attribute__((address_space(1))) void*)g,
        (__attribute__((address_space(3))) void*)l, 16, 0, 0);
}

__device__ __forceinline__ unsigned int pk2(float a, float b) {
    bf16 ha = __float2bfloat16(a), hb = __float2bfloat16(b);
    unsigned short ua, ub;
    __builtin_memcpy(&ua, &ha, 2);
    __builtin_memcpy(&ub, &hb, 2);
    return (unsigned int)ua | ((unsigned int)ub << 16);
}

// ------- fused prep: fp32->bf16 for x / w_qkv / w_out + RoPE tables -------
__global__ void prep(const float* __restrict__ x, const float* __restrict__ wq,
                     const float* __restrict__ wo,
                     bf16* __restrict__ xb, bf16* __restrict__ wqb,
                     bf16* __restrict__ wob, float2* __restrict__ rt) {
    const int gb = blockIdx.x;
    if (gb < 16384) {
        const float* in; bf16* out; int i;
        if (gb < 8192)       { in = x;  out = xb;  i = gb * 256 + threadIdx.x; }
        else if (gb < 14336) { in = wq; out = wqb; i = (gb - 8192) * 256 + threadIdx.x; }
        else                 { in = wo; out = wob; i = (gb - 14336) * 256 + threadIdx.x; }
        const float4* p = (const float4*)in + 2 * (size_t)i;
        float4 a = p[0], b = p[1];
        float v[8] = {a.x, a.y, a.z, a.w, b.x, b.y, b.z, b.w};
        bf16 h[8];
#pragma unroll
        for (int j = 0; j < 8; j++) h[j] = __float2bfloat16(v[j]);
        __builtin_memcpy(out + 8 * (size_t)i, h, 16);
    } else {
        int i = (gb - 16384) * 256 + threadIdx.x;   // S*64 entries
        int s = i >> 6, f = i & 63;
        float inv_freq = powf(10000.0f, -(float)(2 * f) / 128.0f);
        float ang = (float)s * inv_freq;
        rt[i] = make_float2(cosf(ang), sinf(ang));
    }
}

// ---------------- bf16 GEMM: C[M,N] = A[M,K] * B[N,K]^T ----------------
// BK=64; LDS rows are 128 B (8 x 16-B chunks) with XOR-8 swizzle applied at
// the DMA SOURCE so the global_load_lds destination stays linear.
template <int EPI>
__global__ __launch_bounds__(256, 2)
void gemm_bf16(const bf16* __restrict__ A, const bf16* __restrict__ Bm,
               int N, int K,
               float* __restrict__ outF,
               bf16* __restrict__ qb, bf16* __restrict__ kb, bf16* __restrict__ vtb,
               const float2* __restrict__ rope) {
    __shared__ bf16 As[128 * 64];   // 16 KB
    __shared__ bf16 Bs[128 * 64];   // 16 KB
    const int tid = threadIdx.x;
    const int wave = tid >> 6, lane = tid & 63;
    const int quad = lane >> 4, l16 = lane & 15;
    const int wm = wave >> 1, wn = wave & 1;
    const int m0 = blockIdx.y * 128;
    const int n0 = blockIdx.x * 128;

    const int srow = tid >> 3;                      // 0..31
    const int schunk = (tid & 7) ^ (srow & 7);      // swizzled source chunk
    const bf16* apr[4];
    const bf16* bpr[4];
#pragma unroll
    for (int r = 0; r < 4; r++) {
        apr[r] = A  + (size_t)(m0 + r * 32 + srow) * K + schunk * 8;
        bpr[r] = Bm + (size_t)(n0 + r * 32 + srow) * K + schunk * 8;
    }
    bf16* asd = As + tid * 8;
    bf16* bsd = Bs + tid * 8;

    floatx4 acc[4][4] = {};
    const int swz = l16 & 7;

    for (int k0 = 0; k0 < K; k0 += 64) {
        __syncthreads();
#pragma unroll
        for (int r = 0; r < 4; r++) {
            async_ld16(apr[r] + k0, asd + r * 2048);
            async_ld16(bpr[r] + k0, bsd + r * 2048);
        }
        __syncthreads();
#pragma unroll
        for (int kk = 0; kk < 2; kk++) {
            short8 af[4], bfr[4];
#pragma unroll
            for (int i = 0; i < 4; i++)
                af[i] = *(const short8*)(As + (wm * 64 + i * 16 + l16) * 64 + (((kk * 4 + quad) ^ swz) * 8));
#pragma unroll
            for (int j = 0; j < 4; j++)
                bfr[j] = *(const short8*)(Bs + (wn * 64 + j * 16 + l16) * 64 + (((kk * 4 + quad) ^ swz) * 8));
#pragma unroll
            for (int i = 0; i < 4; i++)
#pragma unroll
                for (int j = 0; j < 4; j++)
                    acc[i][j] = __builtin_amdgcn_mfma_f32_16x16x32_bf16(af[i], bfr[j], acc[i][j], 0, 0, 0);
        }
    }

    if (EPI == 0) {
#pragma unroll
        for (int i = 0; i < 4; i++) {
            const int gm0 = m0 + wm * 64 + i * 16 + quad * 4;
#pragma unroll
            for (int j = 0; j < 4; j++) {
                const int gn = n0 + wn * 64 + j * 16 + l16;
#pragma unroll
                for (int r = 0; r < 4; r++)
                    outF[(size_t)(gm0 + r) * N + gn] = acc[i][j][r];
            }
        }
    } else {
        const int t = n0 >> 11;          // 0=q 1=k 2=v
        const int h = (n0 >> 7) & 15;
        const float qscale = 0.08838834764831845f * 1.442695040888963f;
        if (t < 2) {
#pragma unroll
            for (int j = 0; j < 4; j++) {
                const int d = wn * 64 + j * 16 + l16;
#pragma unroll
                for (int i = 0; i < 4; i++) {
#pragma unroll
                    for (int r = 0; r < 4; r++) {
                        const int gm = m0 + wm * 64 + i * 16 + quad * 4 + r;
                        const int b = gm >> 11, s = gm & 2047;
                        const size_t bh = (size_t)(b * Hh + h);
                        float val = acc[i][j][r];
                        float partner = __shfl_xor(val, 1, 64);
                        float2 cs = rope[s * 64 + (d >> 1)];
                        float nv = (d & 1) ? (val * cs.x + partner * cs.y)
                                           : (val * cs.x - partner * cs.y);
                        if (t == 0) {
                            qb[(bh * Ss + s) * DKk + d] = __float2bfloat16(nv * qscale);
                        } else {
                            kb[(bh * Ss + s) * DKk + d] = __float2bfloat16(nv);
                        }
                    }
                }
            }
        } else {
#pragma unroll
            for (int j = 0; j < 4; j++) {
                const int d = wn * 64 + j * 16 + l16;
#pragma unroll
                for (int i = 0; i < 4; i++) {
                    const int gm = m0 + wm * 64 + i * 16 + quad * 4;
                    const int b = gm >> 11, s = gm & 2047;
                    const size_t bh = (size_t)(b * Hh + h);
                    unsigned int w[2];
                    w[0] = pk2(acc[i][j][0], acc[i][j][1]);
                    w[1] = pk2(acc[i][j][2], acc[i][j][3]);
                    __builtin_memcpy(vtb + (bh * DKk + d) * Ss + s, w, 8);
                }
            }
        }
    }
}

// ---------------- flash attention tile body (full vs diagonal) ------------
template <bool DIAG>
__device__ __forceinline__ void attn_tile(
    int c0, int qw0,
    const bf16* __restrict__ kbp, const bf16* __restrict__ vbp,
    bf16* Ks, bf16* Vs,
    const short8 (&qB)[2][4],
    floatx4 (&oacc)[8][2], float (&m_i)[2], float (&l_i)[2],
    int tid, int wave, int quad, int l16, int srow, int chunkg, int swz)
{
    __syncthreads();
#pragma unroll
    for (int r = 0; r < 8; r++) {
        async_ld16(kbp + (size_t)(c0 + r * 16 + srow) * DKk + chunkg * 8,
                   Ks + ((r * 256 + tid) << 3));
        async_ld16(vbp + (size_t)(r * 16 + srow) * Ss + c0 + chunkg * 8,
                   Vs + ((r * 256 + tid) << 3));
    }
    __syncthreads();

    const int lim_n = DIAG ? (wave * 2 + 2) : 8;
    const int lim_k = DIAG ? (wave + 1) : 4;

    // ---- S^T = K Q^T  (q pre-scaled by 1/sqrt(dk)*log2 e) ----
    floatx4 sf[8][2];
#pragma unroll
    for (int n = 0; n < 8; n++) {
        if (n < lim_n) {
            short8 kf[4];
#pragma unroll
            for (int kk = 0; kk < 4; kk++)
                kf[kk] = *(const short8*)(Ks + (n * 16 + l16) * 128 + (((kk * 4 + quad) ^ swz) * 8));
            sf[n][0] = (floatx4){0.f, 0.f, 0.f, 0.f};
            sf[n][1] = (floatx4){0.f, 0.f, 0.f, 0.f};
#pragma unroll
            for (int kk = 0; kk < 4; kk++) {
                sf[n][0] = __builtin_amdgcn_mfma_f32_16x16x32_bf16(kf[kk], qB[0][kk], sf[n][0], 0, 0, 0);
                sf[n][1] = __builtin_amdgcn_mfma_f32_16x16x32_bf16(kf[kk], qB[1][kk], sf[n][1], 0, 0, 0);
            }
        }
    }

    // ---- online softmax (base-2; state per l16 lane, replicated in quads) ----
    unsigned int pp01[8][2], pp23[8][2];
#pragma unroll
    for (int qf = 0; qf < 2; qf++) {
        float mx = -__builtin_inff();
        if (DIAG) {
            const int qrow = qw0 + qf * 16 + l16;
#pragma unroll
            for (int n = 0; n < 8; n++) {
                if (n < lim_n) {
                    const int kvb = c0 + n * 16 + quad * 4;
#pragma unroll
                    for (int r = 0; r < 4; r++) {
                        float v = sf[n][qf][r];
                        v = (kvb + r > qrow) ? -__builtin_inff() : v;
                        sf[n][qf][r] = v;
                        mx = fmaxf(mx, v);
                    }
                }
            }
        } else {
#pragma unroll
            for (int n = 0; n < 8; n++)
#pragma unroll
                for (int r = 0; r < 4; r++) mx = fmaxf(mx, sf[n][qf][r]);
        }
        mx = fmaxf(mx, __shfl_xor(mx, 16, 64));
        mx = fmaxf(mx, __shfl_xor(mx, 32, 64));
        const float mnew = fmaxf(m_i[qf], mx);
        const float alpha = __builtin_amdgcn_exp2f(m_i[qf] - mnew);
        m_i[qf] = mnew;
        float rs = 0.f;
#pragma unroll
        for (int n = 0; n < 8; n++) {
            if (n < lim_n) {
                float p0 = __builtin_amdgcn_exp2f(sf[n][qf][0] - mnew);
                float p1 = __builtin_amdgcn_exp2f(sf[n][qf][1] - mnew);
                float p2 = __builtin_amdgcn_exp2f(sf[n][qf][2] - mnew);
                float p3 = __builtin_amdgcn_exp2f(sf[n][qf][3] - mnew);
                rs += (p0 + p1) + (p2 + p3);
                pp01[n][qf] = pk2(p0, p1);
                pp23[n][qf] = pk2(p2, p3);
            }
        }
        rs += __shfl_xor(rs, 16, 64);
        rs += __shfl_xor(rs, 32, 64);
        l_i[qf] = l_i[qf] * alpha + rs;
#pragma unroll
        for (int md = 0; md < 8; md++)
#pragma unroll
            for (int r = 0; r < 4; r++) oacc[md][qf][r] *= alpha;
    }

    // ---- O^T += V^T P^T  (P^T B-frags built in-register via shuffles) ----
    const int srcA = ((quad & 1) * 2) * 16 + l16;
    const int srcB = srcA + 16;
#pragma unroll
    for (int kv = 0; kv < 4; kv++) {
        if (kv < lim_k) {
            short8 pB[2];
#pragma unroll
            for (int qf = 0; qf < 2; qf++) {
                unsigned int a01 = (unsigned int)__shfl((int)pp01[2 * kv][qf], srcA, 64);
                unsigned int a23 = (unsigned int)__shfl((int)pp23[2 * kv][qf], srcA, 64);
                unsigned int a45 = (unsigned int)__shfl((int)pp01[2 * kv][qf], srcB, 64);
                unsigned int a67 = (unsigned int)__shfl((int)pp23[2 * kv][qf], srcB, 64);
                unsigned int b01 = (unsigned int)__shfl((int)pp01[2 * kv + 1][qf], srcA, 64);
                unsigned int b23 = (unsigned int)__shfl((int)pp23[2 * kv + 1][qf], srcA, 64);
                unsigned int b45 = (unsigned int)__shfl((int)pp01[2 * kv + 1][qf], srcB, 64);
                unsigned int b67 = (unsigned int)__shfl((int)pp23[2 * kv + 1][qf], srcB, 64);
                const bool hi = quad >= 2;
                unsigned int e[4];
                e[0] = hi ? b01 : a01;
                e[1] = hi ? b23 : a23;
                e[2] = hi ? b45 : a45;
                e[3] = hi ? b67 : a67;
                __builtin_memcpy(&pB[qf], e, 16);
            }
#pragma unroll
            for (int md = 0; md < 8; md++) {
                short8 vf = *(const short8*)(Vs + (md * 16 + l16) * 128 + (((kv * 4 + quad) ^ swz) * 8));
                oacc[md][0] = __builtin_amdgcn_mfma_f32_16x16x32_bf16(vf, pB[0], oacc[md][0], 0, 0, 0);
                oacc[md][1] = __builtin_amdgcn_mfma_f32_16x16x32_bf16(vf, pB[1], oacc[md][1], 0, 0, 0);
            }
        }
    }
}

// ---------------- flash attention (balanced q-tile pairing) ----------------
// grid (64, 8): x = bh (head), y = xp (q-tile pair).  Linear dispatch id =
// bh + 64*xp -> XCD = bh % 8: the 8 blocks sharing one head's K/V co-reside
// on ONE XCD's L2 (T1).  (Old (8,64) mapping put them on 8 different XCDs ->
// zero K/V L2 sharing.)  Block xp processes q-tiles {15-xp, xp} sequentially
// -> every block does exactly 17 tile-units; 512 blocks = exactly 2/CU.
__global__ __launch_bounds__(256, 2)
void flash_attn(const bf16* __restrict__ q, const bf16* __restrict__ k,
                const bf16* __restrict__ vt, bf16* __restrict__ o) {
    __shared__ bf16 Ks[128 * 128];   // 32 KB  rows=kv, cols=d
    __shared__ bf16 Vs[128 * 128];   // 32 KB  rows=d,  cols=kv
    const int tid = threadIdx.x, wave = tid >> 6, lane = tid & 63;
    const int quad = lane >> 4, l16 = lane & 15;
    const int bh = blockIdx.x;       // 0..63  (fastest-varying -> XCD = bh%8)
    const int xp = blockIdx.y;       // 0..7
    const bf16* qbp = q  + (size_t)bh * Ss * DKk;
    const bf16* kbp = k  + (size_t)bh * Ss * DKk;
    const bf16* vbp = vt + (size_t)bh * DKk * Ss;
    const int b = bh >> 4, h = bh & 15;

    const int srow = tid >> 4;
    const int chunkg = (tid & 15) ^ (srow & 7);
    const int swz = (l16 & 7);

    for (int pass = 0; pass < 2; ++pass) {
        const int xq = pass ? xp : 15 - xp;
        const int qw0 = xq * 128 + wave * 32;

        short8 qB[2][4];
#pragma unroll
        for (int qf = 0; qf < 2; qf++)
#pragma unroll
            for (int kk = 0; kk < 4; kk++)
                qB[qf][kk] = *(const short8*)(qbp + (size_t)(qw0 + qf * 16 + l16) * DKk + kk * 32 + quad * 8);

        floatx4 oacc[8][2] = {};
        float m_i[2] = {-__builtin_inff(), -__builtin_inff()};
        float l_i[2] = {0.f, 0.f};

        for (int it = 0; it < xq; ++it)
            attn_tile<false>(it * 128, qw0, kbp, vbp, Ks, Vs, qB, oacc, m_i, l_i,
                             tid, wave, quad, l16, srow, chunkg, swz);
        attn_tile<true>(xq * 128, qw0, kbp, vbp, Ks, Vs, qB, oacc, m_i, l_i,
                        tid, wave, quad, l16, srow, chunkg, swz);

#pragma unroll
        for (int qf = 0; qf < 2; qf++) {
            const float inv = 1.0f / l_i[qf];
            const int s = qw0 + qf * 16 + l16;
            bf16* orow = o + (size_t)(b * Ss + s) * Dd + h * 128;
#pragma unroll
            for (int md = 0; md < 8; md++) {
                unsigned int w[2];
                w[0] = pk2(oacc[md][qf][0] * inv, oacc[md][qf][1] * inv);
                w[1] = pk2(oacc[md][qf][2] * inv, oacc[md][qf][3] * inv);
                __builtin_memcpy(orow + md * 16 + quad * 4, w, 8);
            }
        }
    }
}

extern "C" void kernel_launch(void* const* d_in, const int* in_sizes, int n_in,
                              void* d_out, int out_size, void* d_ws, size_t ws_size,
                              hipStream_t stream) {
    const float* x     = (const float*)d_in[0];
    const float* w_qkv = (const float*)d_in[1];
    const float* w_out = (const float*)d_in[2];
    float* out = (float*)d_out;
    char* ws = (char*)d_ws;

    bf16*   xb  = (bf16*)(ws);                 // 32 MiB  x bf16; reused as attn output
    bf16*   wqb = (bf16*)(ws + 33554432);      // 24 MiB  w_qkv bf16
    bf16*   wob = (bf16*)(ws + 58720256);      //  8 MiB  w_out bf16
    bf16*   qb  = (bf16*)(ws + 67108864);      // 32 MiB  q   [B,H,S,dk] (pre-scaled)
    bf16*   kb  = (bf16*)(ws + 100663296);     // 32 MiB  k   [B,H,S,dk]
    bf16*   vtb = (bf16*)(ws + 134217728);     // 32 MiB  v^T [B,H,dk,S]
    float2* rt  = (float2*)(ws + 167772160);   //  1 MiB  rope tables

    prep<<<16896, 256, 0, stream>>>(x, w_qkv, w_out, xb, wqb, wob, rt);

    gemm_bf16<1><<<dim3(48, 64), 256, 0, stream>>>(xb, wqb, 6144, 2048,
                                                   nullptr, qb, kb, vtb, rt);
    flash_attn<<<dim3(64, 8), 256, 0, stream>>>(qb, kb, vtb, xb);
    gemm_bf16<0><<<dim3(16, 64), 256, 0, stream>>>(xb, wob, 2048, 2048,
                                                   out, nullptr, nullptr, nullptr, rt);
}